// Round 1
// baseline (929.184 us; speedup 1.0000x reference)
//
#include <hip/hip_runtime.h>
#include <hip/hip_bf16.h>

typedef __bf16 bf16_t;
typedef bf16_t bf16x8 __attribute__((ext_vector_type(8)));
typedef bf16_t bf16x4 __attribute__((ext_vector_type(4)));
typedef float floatx4 __attribute__((ext_vector_type(4)));

#define S_LEN 2048
#define NHEADS 32
#define HD 128
#define QKV_LD 12288   // 3*H, row stride of qkv buffer

// ---------------- fp32 -> bf16 convert (vectorized) ----------------
__global__ void f32_to_bf16_k(const float* __restrict__ in, bf16_t* __restrict__ out, int n4) {
    int i = blockIdx.x * 256 + threadIdx.x;
    if (i >= n4) return;
    float4 v = ((const float4*)in)[i];
    bf16x4 o;
    o.x = (bf16_t)v.x; o.y = (bf16_t)v.y; o.z = (bf16_t)v.z; o.w = (bf16_t)v.w;
    ((bf16x4*)out)[i] = o;
}

// ---------------- async global->LDS helper ----------------
__device__ __forceinline__ void async_copy16(const void* g, void* l) {
    __builtin_amdgcn_global_load_lds(
        (const __attribute__((address_space(1))) unsigned int*)g,
        (__attribute__((address_space(3))) unsigned int*)l, 16, 0, 0);
}

// ---------------- GEMM: C[m][n] = sum_k A[m][k]*B[n][k] + bias[n] ----------------
// A: M x K bf16 row-major, B: N x K bf16 row-major. 128x128 tile, BK=32.
template<bool OUT_BF16>
__global__ __launch_bounds__(256) void gemm_bt(
    const bf16_t* __restrict__ A, const bf16_t* __restrict__ B,
    const float* __restrict__ bias, void* __restrict__ Cv,
    int M, int N, int K)
{
    __shared__ bf16_t As[128 * 32];
    __shared__ bf16_t Bs[128 * 32];
    const int t    = threadIdx.x;
    const int lane = t & 63;
    const int w    = t >> 6;
    const int l15  = lane & 15;
    const int quad = lane >> 4;
    const int bm = blockIdx.y, bn = blockIdx.x;
    const int mw = (w >> 1) * 64, nw = (w & 1) * 64;

    floatx4 acc[4][4];
    #pragma unroll
    for (int i = 0; i < 4; i++)
        #pragma unroll
        for (int j = 0; j < 4; j++)
            acc[i][j] = (floatx4){0.f, 0.f, 0.f, 0.f};

    const int r0 = t >> 2;            // 0..63
    const int c0 = (t & 3) * 8;       // 0..24
    const bf16_t* Aptr = A + (size_t)(bm * 128 + r0) * K + c0;
    const bf16_t* Bptr = B + (size_t)(bn * 128 + r0) * K + c0;
    bf16_t* AsW = As + t * 8;
    bf16_t* BsW = Bs + t * 8;

    for (int k0 = 0; k0 < K; k0 += 32) {
        __syncthreads();
        async_copy16(Aptr + k0, AsW);
        async_copy16(Aptr + k0 + (size_t)64 * K, AsW + 2048);
        async_copy16(Bptr + k0, BsW);
        async_copy16(Bptr + k0 + (size_t)64 * K, BsW + 2048);
        __syncthreads();

        bf16x8 a[4], b[4];
        #pragma unroll
        for (int mi = 0; mi < 4; mi++)
            a[mi] = *(const bf16x8*)&As[(mw + mi * 16 + l15) * 32 + quad * 8];
        #pragma unroll
        for (int ni = 0; ni < 4; ni++)
            b[ni] = *(const bf16x8*)&Bs[(nw + ni * 16 + l15) * 32 + quad * 8];
        #pragma unroll
        for (int mi = 0; mi < 4; mi++)
            #pragma unroll
            for (int ni = 0; ni < 4; ni++)
                acc[mi][ni] = __builtin_amdgcn_mfma_f32_16x16x32_bf16(a[mi], b[ni], acc[mi][ni], 0, 0, 0);
    }

    // epilogue
    float bv[4];
    #pragma unroll
    for (int ni = 0; ni < 4; ni++)
        bv[ni] = bias[bn * 128 + nw + ni * 16 + l15];
    #pragma unroll
    for (int mi = 0; mi < 4; mi++) {
        #pragma unroll
        for (int ni = 0; ni < 4; ni++) {
            int col = bn * 128 + nw + ni * 16 + l15;
            #pragma unroll
            for (int r = 0; r < 4; r++) {
                int row = bm * 128 + mw + mi * 16 + quad * 4 + r;
                float v = acc[mi][ni][r] + bv[ni];
                if (OUT_BF16)
                    ((bf16_t*)Cv)[(size_t)row * N + col] = (bf16_t)v;
                else
                    ((float*)Cv)[(size_t)row * N + col] = v;
            }
        }
    }
}

// ---------------- RoPE in-place on q,k (first 32 dims per head) ----------------
__global__ void rope_kernel(bf16_t* __restrict__ qkv) {
    int idx = blockIdx.x * 256 + threadIdx.x;   // total 2048*32*16
    int j = idx & 15;
    int h = (idx >> 4) & 31;
    int s = idx >> 9;
    float freq = (float)s * powf(10000.f, -(float)j / 16.f);
    float sn, cs;
    sincosf(freq, &sn, &cs);
    bf16_t* base = qkv + (size_t)s * QKV_LD + h * 384;
    // q
    {
        float x1 = (float)base[j], x2 = (float)base[j + 16];
        base[j]      = (bf16_t)(x1 * cs - x2 * sn);
        base[j + 16] = (bf16_t)(x2 * cs + x1 * sn);
    }
    // k
    {
        bf16_t* kb = base + 128;
        float x1 = (float)kb[j], x2 = (float)kb[j + 16];
        kb[j]      = (bf16_t)(x1 * cs - x2 * sn);
        kb[j + 16] = (bf16_t)(x2 * cs + x1 * sn);
    }
}

// ---------------- V transpose: qkv V part -> Vt[h][d][s] ----------------
__global__ void vtrans_kernel(const bf16_t* __restrict__ qkv, bf16_t* __restrict__ Vt) {
    __shared__ bf16_t tile[64][68];   // row stride 136B: 8B aligned, conflict-lite
    int h = blockIdx.y;
    int stile = blockIdx.x >> 1, dtile = blockIdx.x & 1;
    int t = threadIdx.x;
    int tr = t >> 4;            // 0..15
    int tc4 = (t & 15) * 4;     // 0..60
    const bf16_t* src = qkv + (size_t)(stile * 64) * QKV_LD + h * 384 + 256 + dtile * 64;
    #pragma unroll
    for (int r = 0; r < 4; r++) {
        int srow = tr + r * 16;
        *(bf16x4*)&tile[srow][tc4] = *(const bf16x4*)&src[(size_t)srow * QKV_LD + tc4];
    }
    __syncthreads();
    bf16_t* dst = Vt + ((size_t)h * HD + dtile * 64) * S_LEN + stile * 64;
    #pragma unroll
    for (int r = 0; r < 4; r++) {
        int drow = tr + r * 16;
        bf16x4 v;
        #pragma unroll
        for (int j = 0; j < 4; j++) v[j] = tile[tc4 + j][drow];
        *(bf16x4*)&dst[(size_t)drow * S_LEN + tc4] = v;
    }
}

// ---------------- Flash attention (causal), BQ=64, key tile 64 ----------------
#define QK_LDS 136   // 128+8 shorts
#define V_LDS  72    // 64+8 shorts
__global__ __launch_bounds__(256) void flash_attn(
    const bf16_t* __restrict__ qkv, const bf16_t* __restrict__ Vt,
    bf16_t* __restrict__ ctx)
{
    __shared__ bf16_t Qs[64 * QK_LDS];
    __shared__ bf16_t Ks[64 * QK_LDS];
    __shared__ bf16_t Vs[128 * V_LDS];
    __shared__ bf16_t Ps[64 * V_LDS];
    const int h = blockIdx.y;
    const int qb = blockIdx.x;
    const int t = threadIdx.x;
    const int w = t >> 6, lane = t & 63;
    const int quad = lane >> 4, l15 = lane & 15;
    const float L2E = 1.4426950408889634f;
    const float ISQ = 0.08838834764831845f;   // 1/sqrt(128)

    // stage Q tile (rows qb*64..+63)
    {
        const bf16_t* qbase = qkv + (size_t)(qb * 64) * QKV_LD + h * 384;
        int rr = t >> 4, cc = (t & 15) * 8;
        #pragma unroll
        for (int p = 0; p < 4; p++) {
            int row = rr + p * 16;
            *(bf16x8*)&Qs[row * QK_LDS + cc] = *(const bf16x8*)&qbase[(size_t)row * QKV_LD + cc];
        }
    }

    floatx4 o[8];
    #pragma unroll
    for (int i = 0; i < 8; i++) o[i] = (floatx4){0.f, 0.f, 0.f, 0.f};
    float mrow[4] = {-1e30f, -1e30f, -1e30f, -1e30f};
    float lrow[4] = {0.f, 0.f, 0.f, 0.f};

    for (int kt = 0; kt <= qb; kt++) {
        __syncthreads();
        // stage K tile + Vt tile
        {
            const bf16_t* kbase = qkv + (size_t)(kt * 64) * QKV_LD + h * 384 + 128;
            int rr = t >> 4, cc = (t & 15) * 8;
            #pragma unroll
            for (int p = 0; p < 4; p++) {
                int row = rr + p * 16;
                *(bf16x8*)&Ks[row * QK_LDS + cc] = *(const bf16x8*)&kbase[(size_t)row * QKV_LD + cc];
            }
            const bf16_t* vbase = Vt + (size_t)h * HD * S_LEN + kt * 64;
            int vr = t >> 3, vc = (t & 7) * 8;
            #pragma unroll
            for (int p = 0; p < 4; p++) {
                int row = vr + p * 32;
                *(bf16x8*)&Vs[row * V_LDS + vc] = *(const bf16x8*)&vbase[(size_t)row * S_LEN + vc];
            }
        }
        __syncthreads();

        // S = Q K^T  (wave rows w*16..+15, 64 keys)
        floatx4 sacc[4];
        #pragma unroll
        for (int ni = 0; ni < 4; ni++) sacc[ni] = (floatx4){0.f, 0.f, 0.f, 0.f};
        #pragma unroll
        for (int ks = 0; ks < 4; ks++) {
            bf16x8 aq = *(const bf16x8*)&Qs[(w * 16 + l15) * QK_LDS + ks * 32 + quad * 8];
            #pragma unroll
            for (int ni = 0; ni < 4; ni++) {
                bf16x8 bk = *(const bf16x8*)&Ks[(ni * 16 + l15) * QK_LDS + ks * 32 + quad * 8];
                sacc[ni] = __builtin_amdgcn_mfma_f32_16x16x32_bf16(aq, bk, sacc[ni], 0, 0, 0);
            }
        }

        float p_[4][4];
        #pragma unroll
        for (int ni = 0; ni < 4; ni++)
            #pragma unroll
            for (int r = 0; r < 4; r++)
                p_[ni][r] = sacc[ni][r] * ISQ;
        if (kt == qb) {   // diagonal tile: causal mask
            #pragma unroll
            for (int ni = 0; ni < 4; ni++) {
                int key = ni * 16 + l15;
                #pragma unroll
                for (int r = 0; r < 4; r++)
                    if (key > w * 16 + quad * 4 + r) p_[ni][r] = -1e30f;
            }
        }

        // online softmax (rows = quad*4+r, reduce across 16 lanes of quad)
        float alpha[4];
        #pragma unroll
        for (int r = 0; r < 4; r++) {
            float mx = fmaxf(fmaxf(p_[0][r], p_[1][r]), fmaxf(p_[2][r], p_[3][r]));
            #pragma unroll
            for (int off = 1; off < 16; off <<= 1)
                mx = fmaxf(mx, __shfl_xor(mx, off, 16));
            float mnew = fmaxf(mrow[r], mx);
            alpha[r] = __builtin_amdgcn_exp2f((mrow[r] - mnew) * L2E);
            mrow[r] = mnew;
        }
        float lad[4] = {0.f, 0.f, 0.f, 0.f};
        #pragma unroll
        for (int ni = 0; ni < 4; ni++)
            #pragma unroll
            for (int r = 0; r < 4; r++) {
                float pv = __builtin_amdgcn_exp2f((p_[ni][r] - mrow[r]) * L2E);
                p_[ni][r] = pv;
                lad[r] += pv;
            }
        #pragma unroll
        for (int r = 0; r < 4; r++) {
            #pragma unroll
            for (int off = 1; off < 16; off <<= 1)
                lad[r] += __shfl_xor(lad[r], off, 16);
            lrow[r] = lrow[r] * alpha[r] + lad[r];
        }
        #pragma unroll
        for (int ni = 0; ni < 8; ni++)
            #pragma unroll
            for (int r = 0; r < 4; r++)
                o[ni][r] *= alpha[r];

        // P -> LDS (bf16, A-operand-ready layout)
        #pragma unroll
        for (int ni = 0; ni < 4; ni++)
            #pragma unroll
            for (int r = 0; r < 4; r++)
                Ps[(w * 16 + quad * 4 + r) * V_LDS + ni * 16 + l15] = (bf16_t)p_[ni][r];
        __syncthreads();

        // O += P V  (A-frags from Ps, B-frags from Vs[d][key])
        #pragma unroll
        for (int ks = 0; ks < 2; ks++) {
            bf16x8 ap = *(const bf16x8*)&Ps[(w * 16 + l15) * V_LDS + ks * 32 + quad * 8];
            #pragma unroll
            for (int ni = 0; ni < 8; ni++) {
                bf16x8 bv = *(const bf16x8*)&Vs[(ni * 16 + l15) * V_LDS + ks * 32 + quad * 8];
                o[ni] = __builtin_amdgcn_mfma_f32_16x16x32_bf16(ap, bv, o[ni], 0, 0, 0);
            }
        }
    }

    // epilogue: O / l -> ctx bf16
    float invl[4];
    #pragma unroll
    for (int r = 0; r < 4; r++) invl[r] = 1.f / lrow[r];
    bf16_t* cbase = ctx + (size_t)(qb * 64) * 4096 + h * HD;
    #pragma unroll
    for (int ni = 0; ni < 8; ni++) {
        int col = ni * 16 + l15;
        #pragma unroll
        for (int r = 0; r < 4; r++) {
            int row = w * 16 + quad * 4 + r;
            cbase[(size_t)row * 4096 + col] = (bf16_t)(o[ni][r] * invl[r]);
        }
    }
}

// ---------------- launch ----------------
extern "C" void kernel_launch(void* const* d_in, const int* in_sizes, int n_in,
                              void* d_out, int out_size, void* d_ws, size_t ws_size,
                              hipStream_t stream) {
    const float* hidden = (const float*)d_in[0];
    const float* Wqkv   = (const float*)d_in[2];
    const float* bqkv   = (const float*)d_in[3];
    const float* Wd     = (const float*)d_in[4];
    const float* bd     = (const float*)d_in[5];
    float* out = (float*)d_out;

    char* ws = (char*)d_ws;
    bf16_t* h_bf    = (bf16_t*)(ws);                 // 16,777,216 B
    bf16_t* wqkv_bf = (bf16_t*)(ws + 16777216);      // 100,663,296 B
    bf16_t* wd_bf   = (bf16_t*)(ws + 117440512);     // 33,554,432 B
    bf16_t* qkv     = (bf16_t*)(ws + 150994944);     // 50,331,648 B
    bf16_t* vt      = (bf16_t*)(ws + 201326592);     // 16,777,216 B
    bf16_t* ctx     = (bf16_t*)(ws + 218103808);     // 16,777,216 B  (end 234,881,024)

    f32_to_bf16_k<<<8192,  256, 0, stream>>>(hidden, h_bf,    2097152);
    f32_to_bf16_k<<<49152, 256, 0, stream>>>(Wqkv,   wqkv_bf, 12582912);
    f32_to_bf16_k<<<16384, 256, 0, stream>>>(Wd,     wd_bf,   4194304);

    gemm_bt<true><<<dim3(96, 16), 256, 0, stream>>>(h_bf, wqkv_bf, bqkv, qkv, 2048, 12288, 4096);
    rope_kernel<<<4096, 256, 0, stream>>>(qkv);
    vtrans_kernel<<<dim3(64, 32), 256, 0, stream>>>(qkv, vt);
    flash_attn<<<dim3(32, 32), 256, 0, stream>>>(qkv, vt, ctx);
    gemm_bt<false><<<dim3(32, 16), 256, 0, stream>>>(ctx, wd_bf, bd, out, 2048, 4096, 4096);
}